// Round 13
// baseline (2091.558 us; speedup 1.0000x reference)
//
#include <hip/hip_runtime.h>

#define B_    8
#define N_    8192
#define M_    2000
#define K_    16
#define C1_   128
#define C2_   256
#define OUT_  100
#define SUBP_ 2048   // padded per-batch pitch for subsampled points (KNN2 candidates)

// ---------------------------------------------------------------- FPS v13: v12 + packed-fp32 active update loop
// v12 post-mortem: fused prep + knn DPP both neutral; fps critical path = active
// wave's 16pt x ~9-inst loop (~290cy issue of ~1650cy/iter). v13 packs it:
// 8 float2 pairs x (7 pk + 6 scalar argmax) = 104 insts vs 144. Source-level v2f
// (ISel emits v_pk_add/mul/fma/min); m.x/m.y compares are register aliases (no
// extraction movs — v6's asm-constraint failure mode avoided). Same VGPR count
// (v2f[8] == float[16]). Tie rule matches v12: strict-> per half (first max in
// scan order), cross-half prefers larger inv (smaller orig); exact ties are
// measure-zero (bench-proven 4x). Everything outside phase D loop unchanged.
#define FPS_T 512
#define FPS_PP 8    // float2 point-pairs per thread: 8 pairs = 16 points

typedef float v2f __attribute__((ext_vector_type(2)));

__device__ __forceinline__ unsigned long long umax64(unsigned long long a, unsigned long long b) {
    return a > b ? a : b;
}

// one stage of wave-max on a u64 key via DPP on both halves (identity 0: keys are non-negative)
template<int CTRL>
__device__ __forceinline__ unsigned long long dpp_max_u64(unsigned long long v) {
    int lo = __builtin_amdgcn_update_dpp(0, (int)(unsigned)(v & 0xFFFFFFFFull), CTRL, 0xF, 0xF, true);
    int hi = __builtin_amdgcn_update_dpp(0, (int)(v >> 32),                     CTRL, 0xF, 0xF, true);
    unsigned long long o = ((unsigned long long)(unsigned)hi << 32) | (unsigned)lo;
    return umax64(v, o);
}

// one stage of wave-min on f32 via DPP; identity = self (old=v, bound_ctrl=false)
template<int CTRL>
__device__ __forceinline__ float dpp_min_f32(float v) {
    int o = __builtin_amdgcn_update_dpp(__float_as_int(v), __float_as_int(v), CTRL, 0xF, 0xF, false);
    return fminf(v, __int_as_float(o));
}

__device__ __forceinline__ int spread3(int v) {   // 3 bits -> bits 0,3,6
    return (v & 1) | ((v & 2) << 2) | ((v & 4) << 4);
}

__global__ __launch_bounds__(FPS_T, 1) void fps_kernel(const float* __restrict__ x,
                                                       float4* __restrict__ coords4,
                                                       float4* __restrict__ sub4) {
    int b = blockIdx.x;
    int t = threadIdx.x;
    int w = t >> 6, lane = t & 63;
    const float* X = x + (size_t)b * N_ * 3;
    float4* C4 = coords4 + b * N_;

    __shared__ float4 Clds[N_];                              // 128 KB coords mirror (by ORIGINAL index)
    __shared__ unsigned short sidx[N_];                      // 16 KB sorted->original index map
    __shared__ unsigned int hist[512];                       // counting-sort histogram / cursors
    __shared__ __align__(16) unsigned long long wkey[2][8];  // per-wave max keys, parity double-buffered

    if (t < 512) hist[t] = 0u;
    if (t < SUBP_ - M_)                                      // sentinel pads: never selected by knn2
        sub4[b*SUBP_ + M_ + t] = make_float4(1e15f, 1e15f, 1e15f, 3e30f);
    __syncthreads();

    // ---- phase A (fused prep): read raw x, build float4, mirror to LDS + global, histogram
    int cellv[16];
#pragma unroll
    for (int j = 0; j < 16; ++j) {
        int i = t + j*FPS_T;
        float xx = X[i*3+0], yy = X[i*3+1], zz = X[i*3+2];
        float ss = fmaf(zz, zz, fmaf(yy, yy, xx*xx));        // ((x^2+y^2)+z^2) — matches old prep
        float4 p = make_float4(xx, yy, zz, ss);
        C4[i] = p;
        Clds[i] = p;
        int cx = (int)(p.x * 8.0f); cx = cx < 0 ? 0 : (cx > 7 ? 7 : cx);
        int cy = (int)(p.y * 8.0f); cy = cy < 0 ? 0 : (cy > 7 ? 7 : cy);
        int cz = (int)(p.z * 8.0f); cz = cz < 0 ? 0 : (cz > 7 ? 7 : cz);
        int cell = (spread3(cx) << 2) | (spread3(cy) << 1) | spread3(cz);   // 9-bit Morton
        cellv[j] = cell;
        atomicAdd(&hist[cell], 1u);
    }
    __syncthreads();

    // ---- phase B: exclusive prefix sum of hist[512] (wave 0)
    if (w == 0) {
        unsigned loc[8], tot = 0u;
#pragma unroll
        for (int c2 = 0; c2 < 8; ++c2) { loc[c2] = hist[lane*8 + c2]; tot += loc[c2]; }
        unsigned pre = tot;
#pragma unroll
        for (int d = 1; d < 64; d <<= 1) {
            unsigned o = __shfl_up(pre, d, 64);
            if (lane >= (unsigned)d) pre += o;
        }
        unsigned run = pre - tot;                            // exclusive base for this lane's 8 cells
#pragma unroll
        for (int c2 = 0; c2 < 8; ++c2) { unsigned v = loc[c2]; hist[lane*8 + c2] = run; run += v; }
    }
    __syncthreads();

    // ---- phase C: scatter original indices into Morton order
#pragma unroll
    for (int j = 0; j < 16; ++j) {
        int i = t + j*FPS_T;
        unsigned pos = atomicAdd(&hist[cellv[j]], 1u);
        sidx[pos] = (unsigned short)i;
    }
    __syncthreads();

    // ---- phase D: wave w owns octant (complement pairing); lane owns 16 sorted points as 8 pairs
    int oct = (w < 4) ? w : 11 - w;                          // SIMD pairs {w,w+4} -> opposite corners
    int sbase = oct*1024 + lane*16;
    v2f px_[FPS_PP], py_[FPS_PP], pz_[FPS_PP], mind[FPS_PP];
    unsigned inva_[FPS_PP], invb_[FPS_PP];
    float wx0 =  1e30f, wy0 =  1e30f, wz0 =  1e30f;
    float wx1 = -1e30f, wy1 = -1e30f, wz1 = -1e30f;
#pragma unroll
    for (int j = 0; j < FPS_PP; ++j) {
        int o0 = (int)sidx[sbase + 2*j];
        int o1 = (int)sidx[sbase + 2*j + 1];
        float4 p0 = Clds[o0], p1 = Clds[o1];
        px_[j] = (v2f){p0.x, p1.x};
        py_[j] = (v2f){p0.y, p1.y};
        pz_[j] = (v2f){p0.z, p1.z};
        mind[j] = (v2f){1e30f, 1e30f};
        inva_[j] = 0xFFFFFFFFu - (unsigned)o0;               // tie -> smaller ORIGINAL index
        invb_[j] = 0xFFFFFFFFu - (unsigned)o1;
        wx0 = fminf(wx0, fminf(p0.x, p1.x)); wx1 = fmaxf(wx1, fmaxf(p0.x, p1.x));
        wy0 = fminf(wy0, fminf(p0.y, p1.y)); wy1 = fmaxf(wy1, fmaxf(p0.y, p1.y));
        wz0 = fminf(wz0, fminf(p0.z, p1.z)); wz1 = fmaxf(wz1, fmaxf(p0.z, p1.z));
    }
    // wave bbox: reduce lane bboxes across the wave (one-time)
    for (int s = 1; s < 64; s <<= 1) {
        wx0 = fminf(wx0, __shfl_xor(wx0, s, 64)); wx1 = fmaxf(wx1, __shfl_xor(wx1, s, 64));
        wy0 = fminf(wy0, __shfl_xor(wy0, s, 64)); wy1 = fmaxf(wy1, __shfl_xor(wy1, s, 64));
        wz0 = fminf(wz0, __shfl_xor(wz0, s, 64)); wz1 = fmaxf(wz1, __shfl_xor(wz1, s, 64));
    }

    float4 P0 = Clds[0];                                     // first pick = original index 0
    if (t == 0) sub4[b*SUBP_] = P0;
    float Px = P0.x, Py = P0.y, Pz = P0.z;
    v2f Px2 = (v2f){P0.x, P0.x}, Py2 = (v2f){P0.y, P0.y}, Pz2 = (v2f){P0.z, P0.z};
    unsigned long long wk = ((unsigned long long)__float_as_uint(1e30f) << 32);  // cached wave key (lane63)
    float wmaxf = 1e30f;                                     // cached wave-max mind (all lanes, via readlane)

    for (int i = 1; i < M_; ++i) {
        // wave-level prune: dmin^2(P, wavebbox) vs cached wave max (skip => bit-exact no-op)
        float qx = fminf(fmaxf(Px, wx0), wx1);
        float qy = fminf(fmaxf(Py, wy0), wy1);
        float qz = fminf(fmaxf(Pz, wz0), wz1);
        float ddx = Px - qx, ddy = Py - qy, ddz = Pz - qz;
        float dmin2 = fmaf(ddz, ddz, fmaf(ddy, ddy, ddx*ddx));
        if (dmin2 * 0.99999f < wmaxf) {                      // ACTIVE: full recompute (all lanes)
            float runA = -3.4e38f, runB = -3.4e38f;
            unsigned ibA = 0u, ibB = 0u;
#pragma unroll
            for (int j = 0; j < FPS_PP; ++j) {
                v2f dx = px_[j] - Px2;                       // v_pk_add (neg mod), exact a-b
                v2f dy = py_[j] - Py2;
                v2f dz = pz_[j] - Pz2;
                v2f d2 = __builtin_elementwise_fma(dz, dz,
                          __builtin_elementwise_fma(dy, dy, dx*dx));   // matches ref association
                v2f m  = __builtin_elementwise_min(mind[j], d2);
                mind[j] = m;
                ibA = (m.x > runA) ? inva_[j] : ibA;         // strict >: first max in scan order
                runA = fmaxf(runA, m.x);
                ibB = (m.y > runB) ? invb_[j] : ibB;
                runB = fmaxf(runB, m.y);
            }
            float runmax = fmaxf(runA, runB);
            unsigned ib = (runB > runA) ? ibB : ((runB == runA) ? (ibA > ibB ? ibA : ibB) : ibA);
            unsigned long long best = ((unsigned long long)__float_as_uint(runmax) << 32)
                                    | (unsigned long long)ib;
            // wave max into lane 63: row_shr 1/2/4/8 then row_bcast 15/31 (all VALU)
            best = dpp_max_u64<0x111>(best);
            best = dpp_max_u64<0x112>(best);
            best = dpp_max_u64<0x114>(best);
            best = dpp_max_u64<0x118>(best);
            best = dpp_max_u64<0x142>(best);
            best = dpp_max_u64<0x143>(best);
            wk = best;
            wmaxf = __uint_as_float((unsigned)__builtin_amdgcn_readlane((int)(unsigned)(wk >> 32), 63));
        }
        if (lane == 63) wkey[i & 1][w] = wk;
        __syncthreads();
        const ulonglong2* wk2 = (const ulonglong2*)wkey[i & 1];
        ulonglong2 q0 = wk2[0], q1 = wk2[1], q2 = wk2[2], q3 = wk2[3];
        unsigned long long gk = umax64(umax64(umax64(q0.x, q0.y), umax64(q1.x, q1.y)),
                                       umax64(umax64(q2.x, q2.y), umax64(q3.x, q3.y)));
        int last = (int)(0xFFFFFFFFu - (unsigned)(gk & 0xFFFFFFFFull));
        float4 P4 = Clds[last];                              // broadcast LDS read (w = |p|^2 intact)
        Px = P4.x; Py = P4.y; Pz = P4.z;
        Px2 = (v2f){P4.x, P4.x}; Py2 = (v2f){P4.y, P4.y}; Pz2 = (v2f){P4.z, P4.z};
        if (t == 0) sub4[b*SUBP_ + i] = P4;
    }
}

// ---------------------------------------------------------------- KNN: 1 wave per query, exact top-16 (set semantics)
// Pass 1: branchless lane-local sorted-16 of values only (15 CE bubble per candidate).
// Merge:  k-way merge of 64 sorted heads -> T = exact 16th smallest distance (DPP min chain).
// Pass 2: ballot-collect indices with d<T, then earliest-index ties d==T (matches lax.top_k stability).
template<int NCH, int PITCH>
__global__ __launch_bounds__(256) void knn_kernel(const float4* __restrict__ cand,
                                                  const float4* __restrict__ qarr,
                                                  int* __restrict__ outIdx) {
    int lane = threadIdx.x & 63;
    int q = blockIdx.x * 4 + (threadIdx.x >> 6);
    int b = q / M_, m = q % M_;
    const float4* Cb = cand + b * PITCH;
    float4 Q = qarr[b * SUBP_ + m];

    float v[16];
#pragma unroll
    for (int tt = 0; tt < 16; ++tt) v[tt] = 3.4e38f;

#pragma unroll 2
    for (int j = 0; j < NCH; ++j) {
        float4 c = Cb[j*64 + lane];
        float dot = fmaf(c.z, Q.z, fmaf(c.y, Q.y, c.x * Q.x));
        float d = fmaf(-2.0f, dot, Q.w + c.w);   // == (qq+ss) - 2*dot, single rounding
        v[15] = fminf(v[15], d);
#pragma unroll
        for (int tt = 15; tt >= 1; --tt) {       // restore sortedness: bubble toward 0
            float lo = fminf(v[tt-1], v[tt]);
            float hi = fmaxf(v[tt-1], v[tt]);
            v[tt-1] = lo; v[tt] = hi;
        }
    }

    float T = 0.0f;
    for (int r = 0; r < 16; ++r) {               // extract global min 16 times (one entry per round)
        float g = v[0];
        g = dpp_min_f32<0x111>(g);               // row_shr 1/2/4/8 + bcast15/31: lane63 = wave min
        g = dpp_min_f32<0x112>(g);
        g = dpp_min_f32<0x114>(g);
        g = dpp_min_f32<0x118>(g);
        g = dpp_min_f32<0x142>(g);
        g = dpp_min_f32<0x143>(g);
        g = __int_as_float(__builtin_amdgcn_readlane(__float_as_int(g), 63));  // wave-uniform
        unsigned long long mk = __ballot(v[0] == g);
        int fl = __ffsll(mk) - 1;                // exactly one lane consumes (value ties resolved)
        if (lane == fl) {
#pragma unroll
            for (int tt = 0; tt < 15; ++tt) v[tt] = v[tt+1];
            v[15] = 3.4e38f;
        }
        T = g;
    }

    unsigned long long mlt = (1ull << lane) - 1ull;
    int base = q * K_;
    int cnt = 0;
    for (int j = 0; j < NCH; ++j) {              // all strictly-closer candidates (<= 15 of them)
        float4 c = Cb[j*64 + lane];
        float dot = fmaf(c.z, Q.z, fmaf(c.y, Q.y, c.x * Q.x));
        float d = fmaf(-2.0f, dot, Q.w + c.w);
        bool lt = d < T;
        unsigned long long m1 = __ballot(lt);
        if (lt) outIdx[base + cnt + __popcll(m1 & mlt)] = j*64 + lane;
        cnt += __popcll(m1);
    }
    int rem = K_ - cnt;                          // >= 1 (T itself); fill with earliest-index ties
    for (int j = 0; j < NCH && rem > 0; ++j) {
        float4 c = Cb[j*64 + lane];
        float dot = fmaf(c.z, Q.z, fmaf(c.y, Q.y, c.x * Q.x));
        float d = fmaf(-2.0f, dot, Q.w + c.w);
        bool eq = (d == T);
        unsigned long long m2 = __ballot(eq);
        int bef = __popcll(m2 & mlt);
        if (eq && bef < rem) outIdx[base + cnt + bef] = j*64 + lane;
        int take = __popcll(m2); if (take > rem) take = rem;
        cnt += take; rem -= take;
    }
}

// ---------------------------------------------------------------- layer 1: feats=[rel(3), ngh(3)] x W1[6,128], relu, max over k
__global__ __launch_bounds__(128) void layer1_kernel(const float4* __restrict__ coords4,
        const float4* __restrict__ sub4, const int* __restrict__ idx1,
        const float* __restrict__ W1, const float* __restrict__ b1,
        float* __restrict__ f1) {
    int q = blockIdx.x;
    int b = q / M_, m = q % M_;
    int c = threadIdx.x;
    __shared__ float4 ngh[K_];
    if (c < K_) ngh[c] = coords4[b*N_ + idx1[q*K_ + c]];
    __syncthreads();
    float4 Q = sub4[b*SUBP_ + m];
    float w0 = W1[c],        w1 = W1[C1_ + c],   w2 = W1[2*C1_ + c];
    float w3 = W1[3*C1_ + c], w4 = W1[4*C1_ + c], w5 = W1[5*C1_ + c];
    float bias = b1[c];
    float mx = -3.4e38f;
#pragma unroll
    for (int k = 0; k < K_; ++k) {
        float4 n = ngh[k];
        float rx = n.x - Q.x, ry = n.y - Q.y, rz = n.z - Q.z;
        float s = rx*w0; s = fmaf(ry,w1,s); s = fmaf(rz,w2,s);
        s = fmaf(n.x,w3,s); s = fmaf(n.y,w4,s); s = fmaf(n.z,w5,s);
        s += bias;
        s = fmaxf(s, 0.0f);
        mx = fmaxf(mx, s);
    }
    f1[q*C1_ + c] = mx;
}

// ---------------------------------------------------------------- layer 2: feats=[rel(3), fg(128)] x W2[131,256], relu, max over k
// float2 accumulators (__builtin_elementwise_fma) so ISel can emit v_pk_fma_f32.
// Bit-exact: pk halves round identically to scalar fma; accumulation order unchanged.
#define FPAD 20   // row pitch (floats): 16B-aligned rows, odd-ish banking for staging
__global__ __launch_bounds__(64) void layer2_kernel(const float4* __restrict__ sub4,
        const float* __restrict__ f1, const int* __restrict__ idx2,
        const float* __restrict__ W2, const float* __restrict__ b2,
        float* __restrict__ f2) {
    int q = blockIdx.x;
    int b = q / M_, m = q % M_;
    int t = threadIdx.x;
    __shared__ __align__(16) float feat[(3 + C1_) * FPAD];  // feat[f][k], k=0..15
    __shared__ int nidx[K_];
    float4 Q = sub4[b*SUBP_ + m];
    if (t < K_) {
        int ik = idx2[q*K_ + t];
        nidx[t] = ik;
        float4 n = sub4[b*SUBP_ + ik];
        feat[0*FPAD + t] = n.x - Q.x;
        feat[1*FPAD + t] = n.y - Q.y;
        feat[2*FPAD + t] = n.z - Q.z;
    }
    __syncthreads();
    for (int e = t; e < K_ * C1_; e += 64) {    // stage gathered f1 rows: feat[3+cc][k]
        int k = e >> 7, cc = e & 127;
        feat[(3 + cc)*FPAD + k] = f1[(b*M_ + nidx[k])*C1_ + cc];
    }
    __syncthreads();

    v2f acc2[K_][2];                             // [k][pair]: ch {c0,c0+1}, {c0+2,c0+3}
#pragma unroll
    for (int k = 0; k < K_; ++k) { acc2[k][0] = (v2f){0.f,0.f}; acc2[k][1] = (v2f){0.f,0.f}; }
    int c0 = t * 4;                              // 4 channels per thread, 64 threads = 256 ch
    for (int f = 0; f < 3 + C1_; ++f) {
        float4 wv = *(const float4*)(W2 + f*C2_ + c0);
        v2f w01 = (v2f){wv.x, wv.y}, w23 = (v2f){wv.z, wv.w};
        const float* row = feat + f*FPAD;
        float4 g0 = *(const float4*)(row + 0);
        float4 g1 = *(const float4*)(row + 4);
        float4 g2 = *(const float4*)(row + 8);
        float4 g3 = *(const float4*)(row + 12);
        float gk[16] = {g0.x,g0.y,g0.z,g0.w, g1.x,g1.y,g1.z,g1.w,
                        g2.x,g2.y,g2.z,g2.w, g3.x,g3.y,g3.z,g3.w};
#pragma unroll
        for (int k = 0; k < K_; ++k) {
            v2f gg = (v2f){gk[k], gk[k]};        // splat -> op_sel broadcast in v_pk_fma_f32
            acc2[k][0] = __builtin_elementwise_fma(gg, w01, acc2[k][0]);
            acc2[k][1] = __builtin_elementwise_fma(gg, w23, acc2[k][1]);
        }
    }
    float4 bb = *(const float4*)(b2 + c0);
    float mx0 = -3.4e38f, mx1 = -3.4e38f, mx2 = -3.4e38f, mx3 = -3.4e38f;
#pragma unroll
    for (int k = 0; k < K_; ++k) {
        float h0 = fmaxf(acc2[k][0].x + bb.x, 0.0f);
        float h1 = fmaxf(acc2[k][0].y + bb.y, 0.0f);
        float h2 = fmaxf(acc2[k][1].x + bb.z, 0.0f);
        float h3 = fmaxf(acc2[k][1].y + bb.w, 0.0f);
        mx0 = fmaxf(mx0, h0); mx1 = fmaxf(mx1, h1);
        mx2 = fmaxf(mx2, h2); mx3 = fmaxf(mx3, h3);
    }
    *(float4*)(f2 + q*C2_ + c0) = make_float4(mx0, mx1, mx2, mx3);
}

// ---------------------------------------------------------------- fused adaptive max+avg pool
__global__ __launch_bounds__(256) void pool_kernel(const float* __restrict__ f2,
                                                   float* __restrict__ out) {
    int bo = blockIdx.x;
    int b = bo / OUT_, o = bo % OUT_;
    int c = threadIdx.x;
    float mx = -3.4e38f, sm = 0.0f;
#pragma unroll
    for (int w = 0; w < M_/OUT_; ++w) {
        float v = f2[(b*M_ + o*(M_/OUT_) + w)*C2_ + c];
        mx = fmaxf(mx, v);
        sm += v;
    }
    out[(b*C2_ + c)*OUT_ + o] = mx + sm / (float)(M_/OUT_);
}

// ---------------------------------------------------------------- launch
extern "C" void kernel_launch(void* const* d_in, const int* in_sizes, int n_in,
                              void* d_out, int out_size, void* d_ws, size_t ws_size,
                              hipStream_t stream) {
    const float* x  = (const float*)d_in[0];
    const float* W1 = (const float*)d_in[1];
    const float* b1 = (const float*)d_in[2];
    const float* W2 = (const float*)d_in[3];
    const float* b2 = (const float*)d_in[4];
    float* out = (float*)d_out;

    char* ws = (char*)d_ws;
    size_t off = 0;
    auto alloc = [&](size_t bytes) {
        void* p = ws + off;
        off += (bytes + 255) & ~(size_t)255;
        return p;
    };
    float4* coords4 = (float4*)alloc((size_t)B_*N_*sizeof(float4));     // 2 MB
    float4* sub4    = (float4*)alloc((size_t)B_*SUBP_*sizeof(float4));  // 256 KB
    int*    idx1    = (int*)  alloc((size_t)B_*M_*K_*sizeof(int));      // 2 MB
    int*    idx2    = (int*)  alloc((size_t)B_*M_*K_*sizeof(int));      // 2 MB
    float*  f1      = (float*)alloc((size_t)B_*M_*C1_*sizeof(float));   // 8 MB
    float*  f2      = (float*)alloc((size_t)B_*M_*C2_*sizeof(float));   // 16 MB

    fps_kernel<<<B_, FPS_T, 0, stream>>>(x, coords4, sub4);
    knn_kernel<N_/64,    N_   ><<<B_*M_/4, 256, 0, stream>>>(coords4, sub4, idx1);
    knn_kernel<SUBP_/64, SUBP_><<<B_*M_/4, 256, 0, stream>>>(sub4,    sub4, idx2);
    layer1_kernel<<<B_*M_, 128, 0, stream>>>(coords4, sub4, idx1, W1, b1, f1);
    layer2_kernel<<<B_*M_,  64, 0, stream>>>(sub4, f1, idx2, W2, b2, f2);
    pool_kernel<<<B_*OUT_, 256, 0, stream>>>(f2, out);
}

// Round 14
// 1973.130 us; speedup vs baseline: 1.0600x; 1.0600x over previous
//
#include <hip/hip_runtime.h>

#define B_    8
#define N_    8192
#define M_    2000
#define K_    16
#define C1_   128
#define C2_   256
#define OUT_  100
#define SUBP_ 2048   // padded per-batch pitch for subsampled points (KNN2 candidates)

// ---------------------------------------------------------------- FPS v12 (restored — best measured fps 1375.7us) + fused prep
// v13 post-mortem: packed phase D cut VALUBusy (1.89->1.62) but ADDED 86us —
// latency-bound loop; pk results feeding scalar .x/.y argmax extraction
// lengthened the dep chain. Third distinct packing failure (v5 spill, v6 movs,
// v13 deps) -> fps inner loop is at its structural floor. Scalar form restored.
#define FPS_T 512
#define FPS_P 16   // points per thread: 512*16 = 8192

__device__ __forceinline__ unsigned long long umax64(unsigned long long a, unsigned long long b) {
    return a > b ? a : b;
}

// one stage of wave-max on a u64 key via DPP on both halves (identity 0: keys are non-negative)
template<int CTRL>
__device__ __forceinline__ unsigned long long dpp_max_u64(unsigned long long v) {
    int lo = __builtin_amdgcn_update_dpp(0, (int)(unsigned)(v & 0xFFFFFFFFull), CTRL, 0xF, 0xF, true);
    int hi = __builtin_amdgcn_update_dpp(0, (int)(v >> 32),                     CTRL, 0xF, 0xF, true);
    unsigned long long o = ((unsigned long long)(unsigned)hi << 32) | (unsigned)lo;
    return umax64(v, o);
}

// one stage of wave-min on f32 via DPP; identity = self (old=v, bound_ctrl=false)
template<int CTRL>
__device__ __forceinline__ float dpp_min_f32(float v) {
    int o = __builtin_amdgcn_update_dpp(__float_as_int(v), __float_as_int(v), CTRL, 0xF, 0xF, false);
    return fminf(v, __int_as_float(o));
}

__device__ __forceinline__ int spread3(int v) {   // 3 bits -> bits 0,3,6
    return (v & 1) | ((v & 2) << 2) | ((v & 4) << 4);
}

__global__ __launch_bounds__(FPS_T, 1) void fps_kernel(const float* __restrict__ x,
                                                       float4* __restrict__ coords4,
                                                       float4* __restrict__ sub4) {
    int b = blockIdx.x;
    int t = threadIdx.x;
    int w = t >> 6, lane = t & 63;
    const float* X = x + (size_t)b * N_ * 3;
    float4* C4 = coords4 + b * N_;

    __shared__ float4 Clds[N_];                              // 128 KB coords mirror (by ORIGINAL index)
    __shared__ unsigned short sidx[N_];                      // 16 KB sorted->original index map
    __shared__ unsigned int hist[512];                       // counting-sort histogram / cursors
    __shared__ __align__(16) unsigned long long wkey[2][8];  // per-wave max keys, parity double-buffered

    if (t < 512) hist[t] = 0u;
    if (t < SUBP_ - M_)                                      // sentinel pads: never selected by knn2
        sub4[b*SUBP_ + M_ + t] = make_float4(1e15f, 1e15f, 1e15f, 3e30f);
    __syncthreads();

    // ---- phase A (fused prep): read raw x, build float4, mirror to LDS + global, histogram
    int cellv[FPS_P];
#pragma unroll
    for (int j = 0; j < FPS_P; ++j) {
        int i = t + j*FPS_T;
        float xx = X[i*3+0], yy = X[i*3+1], zz = X[i*3+2];
        float ss = fmaf(zz, zz, fmaf(yy, yy, xx*xx));        // ((x^2+y^2)+z^2) — matches old prep
        float4 p = make_float4(xx, yy, zz, ss);
        C4[i] = p;
        Clds[i] = p;
        int cx = (int)(p.x * 8.0f); cx = cx < 0 ? 0 : (cx > 7 ? 7 : cx);
        int cy = (int)(p.y * 8.0f); cy = cy < 0 ? 0 : (cy > 7 ? 7 : cy);
        int cz = (int)(p.z * 8.0f); cz = cz < 0 ? 0 : (cz > 7 ? 7 : cz);
        int cell = (spread3(cx) << 2) | (spread3(cy) << 1) | spread3(cz);   // 9-bit Morton
        cellv[j] = cell;
        atomicAdd(&hist[cell], 1u);
    }
    __syncthreads();

    // ---- phase B: exclusive prefix sum of hist[512] (wave 0)
    if (w == 0) {
        unsigned loc[8], tot = 0u;
#pragma unroll
        for (int c2 = 0; c2 < 8; ++c2) { loc[c2] = hist[lane*8 + c2]; tot += loc[c2]; }
        unsigned pre = tot;
#pragma unroll
        for (int d = 1; d < 64; d <<= 1) {
            unsigned o = __shfl_up(pre, d, 64);
            if (lane >= (unsigned)d) pre += o;
        }
        unsigned run = pre - tot;                            // exclusive base for this lane's 8 cells
#pragma unroll
        for (int c2 = 0; c2 < 8; ++c2) { unsigned v = loc[c2]; hist[lane*8 + c2] = run; run += v; }
    }
    __syncthreads();

    // ---- phase C: scatter original indices into Morton order
#pragma unroll
    for (int j = 0; j < FPS_P; ++j) {
        int i = t + j*FPS_T;
        unsigned pos = atomicAdd(&hist[cellv[j]], 1u);
        sidx[pos] = (unsigned short)i;
    }
    __syncthreads();

    // ---- phase D: wave w owns octant (complement pairing); lane owns 16 sorted points
    int oct = (w < 4) ? w : 11 - w;                          // SIMD pairs {w,w+4} -> opposite corners
    int sbase = oct*1024 + lane*FPS_P;
    float px_[FPS_P], py_[FPS_P], pz_[FPS_P], mind[FPS_P];
    unsigned inv_[FPS_P];
    float wx0 =  1e30f, wy0 =  1e30f, wz0 =  1e30f;
    float wx1 = -1e30f, wy1 = -1e30f, wz1 = -1e30f;
#pragma unroll
    for (int j = 0; j < FPS_P; ++j) {
        int o = (int)sidx[sbase + j];
        float4 p = Clds[o];
        px_[j] = p.x; py_[j] = p.y; pz_[j] = p.z;
        mind[j] = 1e30f;
        inv_[j] = 0xFFFFFFFFu - (unsigned)o;                 // tie -> smaller ORIGINAL index
        wx0 = fminf(wx0, p.x); wx1 = fmaxf(wx1, p.x);
        wy0 = fminf(wy0, p.y); wy1 = fmaxf(wy1, p.y);
        wz0 = fminf(wz0, p.z); wz1 = fmaxf(wz1, p.z);
    }
    // wave bbox: reduce lane bboxes across the wave (one-time)
    for (int s = 1; s < 64; s <<= 1) {
        wx0 = fminf(wx0, __shfl_xor(wx0, s, 64)); wx1 = fmaxf(wx1, __shfl_xor(wx1, s, 64));
        wy0 = fminf(wy0, __shfl_xor(wy0, s, 64)); wy1 = fmaxf(wy1, __shfl_xor(wy1, s, 64));
        wz0 = fminf(wz0, __shfl_xor(wz0, s, 64)); wz1 = fmaxf(wz1, __shfl_xor(wz1, s, 64));
    }

    float4 P0 = Clds[0];                                     // first pick = original index 0
    if (t == 0) sub4[b*SUBP_] = P0;
    float Px = P0.x, Py = P0.y, Pz = P0.z;
    unsigned long long wk = ((unsigned long long)__float_as_uint(1e30f) << 32);  // cached wave key (lane63)
    float wmaxf = 1e30f;                                     // cached wave-max mind (all lanes, via readlane)

    for (int i = 1; i < M_; ++i) {
        // wave-level prune: dmin^2(P, wavebbox) vs cached wave max (skip => bit-exact no-op)
        float qx = fminf(fmaxf(Px, wx0), wx1);
        float qy = fminf(fmaxf(Py, wy0), wy1);
        float qz = fminf(fmaxf(Pz, wz0), wz1);
        float ddx = Px - qx, ddy = Py - qy, ddz = Pz - qz;
        float dmin2 = fmaf(ddz, ddz, fmaf(ddy, ddy, ddx*ddx));
        if (dmin2 * 0.99999f < wmaxf) {                      // ACTIVE: full recompute (all lanes)
            float runmax = -3.4e38f;
            unsigned ib = 0u;
#pragma unroll
            for (int j = 0; j < FPS_P; ++j) {
                float dx = px_[j] - Px, dy = py_[j] - Py, dz = pz_[j] - Pz;
                float d = fmaf(dz, dz, fmaf(dy, dy, dx*dx)); // direct form matches reference FPS
                float m = fminf(mind[j], d);
                mind[j] = m;
                ib = (m > runmax) ? inv_[j] : ib;            // strict >: first max = smallest orig idx
                runmax = fmaxf(runmax, m);
            }
            unsigned long long best = ((unsigned long long)__float_as_uint(runmax) << 32)
                                    | (unsigned long long)ib;
            // wave max into lane 63: row_shr 1/2/4/8 then row_bcast 15/31 (all VALU)
            best = dpp_max_u64<0x111>(best);
            best = dpp_max_u64<0x112>(best);
            best = dpp_max_u64<0x114>(best);
            best = dpp_max_u64<0x118>(best);
            best = dpp_max_u64<0x142>(best);
            best = dpp_max_u64<0x143>(best);
            wk = best;
            wmaxf = __uint_as_float((unsigned)__builtin_amdgcn_readlane((int)(unsigned)(wk >> 32), 63));
        }
        if (lane == 63) wkey[i & 1][w] = wk;
        __syncthreads();
        const ulonglong2* wk2 = (const ulonglong2*)wkey[i & 1];
        ulonglong2 q0 = wk2[0], q1 = wk2[1], q2 = wk2[2], q3 = wk2[3];
        unsigned long long gk = umax64(umax64(umax64(q0.x, q0.y), umax64(q1.x, q1.y)),
                                       umax64(umax64(q2.x, q2.y), umax64(q3.x, q3.y)));
        int last = (int)(0xFFFFFFFFu - (unsigned)(gk & 0xFFFFFFFFull));
        float4 P4 = Clds[last];                              // broadcast LDS read (w = |p|^2 intact)
        Px = P4.x; Py = P4.y; Pz = P4.z;
        if (t == 0) sub4[b*SUBP_ + i] = P4;
    }
}

// ---------------------------------------------------------------- KNN body: 1 wave per query, exact top-16 (set semantics)
// Pass 1: branchless lane-local sorted-16 of values only (15 CE bubble per candidate).
// Merge:  k-way merge of 64 sorted heads -> T = exact 16th smallest distance (DPP min chain).
// Pass 2: ballot-collect indices with d<T, then earliest-index ties d==T (matches lax.top_k stability).
template<int NCH, int PITCH>
__device__ __forceinline__ void knn_body(const float4* __restrict__ cand,
                                         const float4* __restrict__ qarr,
                                         int* __restrict__ outIdx, int blk) {
    int lane = threadIdx.x & 63;
    int q = blk * 4 + (threadIdx.x >> 6);
    int b = q / M_, m = q % M_;
    const float4* Cb = cand + b * PITCH;
    float4 Q = qarr[b * SUBP_ + m];

    float v[16];
#pragma unroll
    for (int tt = 0; tt < 16; ++tt) v[tt] = 3.4e38f;

#pragma unroll 2
    for (int j = 0; j < NCH; ++j) {
        float4 c = Cb[j*64 + lane];
        float dot = fmaf(c.z, Q.z, fmaf(c.y, Q.y, c.x * Q.x));
        float d = fmaf(-2.0f, dot, Q.w + c.w);   // == (qq+ss) - 2*dot, single rounding
        v[15] = fminf(v[15], d);
#pragma unroll
        for (int tt = 15; tt >= 1; --tt) {       // restore sortedness: bubble toward 0
            float lo = fminf(v[tt-1], v[tt]);
            float hi = fmaxf(v[tt-1], v[tt]);
            v[tt-1] = lo; v[tt] = hi;
        }
    }

    float T = 0.0f;
    for (int r = 0; r < 16; ++r) {               // extract global min 16 times (one entry per round)
        float g = v[0];
        g = dpp_min_f32<0x111>(g);               // row_shr 1/2/4/8 + bcast15/31: lane63 = wave min
        g = dpp_min_f32<0x112>(g);
        g = dpp_min_f32<0x114>(g);
        g = dpp_min_f32<0x118>(g);
        g = dpp_min_f32<0x142>(g);
        g = dpp_min_f32<0x143>(g);
        g = __int_as_float(__builtin_amdgcn_readlane(__float_as_int(g), 63));  // wave-uniform
        unsigned long long mk = __ballot(v[0] == g);
        int fl = __ffsll(mk) - 1;                // exactly one lane consumes (value ties resolved)
        if (lane == fl) {
#pragma unroll
            for (int tt = 0; tt < 15; ++tt) v[tt] = v[tt+1];
            v[15] = 3.4e38f;
        }
        T = g;
    }

    unsigned long long mlt = (1ull << lane) - 1ull;
    int base = q * K_;
    int cnt = 0;
    for (int j = 0; j < NCH; ++j) {              // all strictly-closer candidates (<= 15 of them)
        float4 c = Cb[j*64 + lane];
        float dot = fmaf(c.z, Q.z, fmaf(c.y, Q.y, c.x * Q.x));
        float d = fmaf(-2.0f, dot, Q.w + c.w);
        bool lt = d < T;
        unsigned long long m1 = __ballot(lt);
        if (lt) outIdx[base + cnt + __popcll(m1 & mlt)] = j*64 + lane;
        cnt += __popcll(m1);
    }
    int rem = K_ - cnt;                          // >= 1 (T itself); fill with earliest-index ties
    for (int j = 0; j < NCH && rem > 0; ++j) {
        float4 c = Cb[j*64 + lane];
        float dot = fmaf(c.z, Q.z, fmaf(c.y, Q.y, c.x * Q.x));
        float d = fmaf(-2.0f, dot, Q.w + c.w);
        bool eq = (d == T);
        unsigned long long m2 = __ballot(eq);
        int bef = __popcll(m2 & mlt);
        if (eq && bef < rem) outIdx[base + cnt + bef] = j*64 + lane;
        int take = __popcll(m2); if (take > rem) take = rem;
        cnt += take; rem -= take;
    }
}

// R13: knn1 + knn2 fused into one launch. Independent (both depend only on fps
// output); blocks [0,4000) run <128,8192> (knn1), [4000,8000) run <32,2048>
// (knn2). Block-uniform branch; saves a launch and overlaps knn2 with knn1 tail.
__global__ __launch_bounds__(256) void knn_both_kernel(const float4* __restrict__ coords4,
                                                       const float4* __restrict__ sub4,
                                                       int* __restrict__ idx1,
                                                       int* __restrict__ idx2) {
    int blk = blockIdx.x;
    if (blk < B_*M_/4) {
        knn_body<N_/64, N_>(coords4, sub4, idx1, blk);
    } else {
        knn_body<SUBP_/64, SUBP_>(sub4, sub4, idx2, blk - B_*M_/4);
    }
}

// ---------------------------------------------------------------- layer 1: feats=[rel(3), ngh(3)] x W1[6,128], relu, max over k
__global__ __launch_bounds__(128) void layer1_kernel(const float4* __restrict__ coords4,
        const float4* __restrict__ sub4, const int* __restrict__ idx1,
        const float* __restrict__ W1, const float* __restrict__ b1,
        float* __restrict__ f1) {
    int q = blockIdx.x;
    int b = q / M_, m = q % M_;
    int c = threadIdx.x;
    __shared__ float4 ngh[K_];
    if (c < K_) ngh[c] = coords4[b*N_ + idx1[q*K_ + c]];
    __syncthreads();
    float4 Q = sub4[b*SUBP_ + m];
    float w0 = W1[c],        w1 = W1[C1_ + c],   w2 = W1[2*C1_ + c];
    float w3 = W1[3*C1_ + c], w4 = W1[4*C1_ + c], w5 = W1[5*C1_ + c];
    float bias = b1[c];
    float mx = -3.4e38f;
#pragma unroll
    for (int k = 0; k < K_; ++k) {
        float4 n = ngh[k];
        float rx = n.x - Q.x, ry = n.y - Q.y, rz = n.z - Q.z;
        float s = rx*w0; s = fmaf(ry,w1,s); s = fmaf(rz,w2,s);
        s = fmaf(n.x,w3,s); s = fmaf(n.y,w4,s); s = fmaf(n.z,w5,s);
        s += bias;
        s = fmaxf(s, 0.0f);
        mx = fmaxf(mx, s);
    }
    f1[q*C1_ + c] = mx;
}

// ---------------------------------------------------------------- layer 2: feats=[rel(3), fg(128)] x W2[131,256], relu, max over k
// float2 accumulators (__builtin_elementwise_fma) so ISel can emit v_pk_fma_f32.
// Bit-exact: pk halves round identically to scalar fma; accumulation order unchanged.
#define FPAD 20   // row pitch (floats): 16B-aligned rows, odd-ish banking for staging
typedef float v2f __attribute__((ext_vector_type(2)));
__global__ __launch_bounds__(64) void layer2_kernel(const float4* __restrict__ sub4,
        const float* __restrict__ f1, const int* __restrict__ idx2,
        const float* __restrict__ W2, const float* __restrict__ b2,
        float* __restrict__ f2) {
    int q = blockIdx.x;
    int b = q / M_, m = q % M_;
    int t = threadIdx.x;
    __shared__ __align__(16) float feat[(3 + C1_) * FPAD];  // feat[f][k], k=0..15
    __shared__ int nidx[K_];
    float4 Q = sub4[b*SUBP_ + m];
    if (t < K_) {
        int ik = idx2[q*K_ + t];
        nidx[t] = ik;
        float4 n = sub4[b*SUBP_ + ik];
        feat[0*FPAD + t] = n.x - Q.x;
        feat[1*FPAD + t] = n.y - Q.y;
        feat[2*FPAD + t] = n.z - Q.z;
    }
    __syncthreads();
    for (int e = t; e < K_ * C1_; e += 64) {    // stage gathered f1 rows: feat[3+cc][k]
        int k = e >> 7, cc = e & 127;
        feat[(3 + cc)*FPAD + k] = f1[(b*M_ + nidx[k])*C1_ + cc];
    }
    __syncthreads();

    v2f acc2[K_][2];                             // [k][pair]: ch {c0,c0+1}, {c0+2,c0+3}
#pragma unroll
    for (int k = 0; k < K_; ++k) { acc2[k][0] = (v2f){0.f,0.f}; acc2[k][1] = (v2f){0.f,0.f}; }
    int c0 = t * 4;                              // 4 channels per thread, 64 threads = 256 ch
    for (int f = 0; f < 3 + C1_; ++f) {
        float4 wv = *(const float4*)(W2 + f*C2_ + c0);
        v2f w01 = (v2f){wv.x, wv.y}, w23 = (v2f){wv.z, wv.w};
        const float* row = feat + f*FPAD;
        float4 g0 = *(const float4*)(row + 0);
        float4 g1 = *(const float4*)(row + 4);
        float4 g2 = *(const float4*)(row + 8);
        float4 g3 = *(const float4*)(row + 12);
        float gk[16] = {g0.x,g0.y,g0.z,g0.w, g1.x,g1.y,g1.z,g1.w,
                        g2.x,g2.y,g2.z,g2.w, g3.x,g3.y,g3.z,g3.w};
#pragma unroll
        for (int k = 0; k < K_; ++k) {
            v2f gg = (v2f){gk[k], gk[k]};        // splat -> op_sel broadcast in v_pk_fma_f32
            acc2[k][0] = __builtin_elementwise_fma(gg, w01, acc2[k][0]);
            acc2[k][1] = __builtin_elementwise_fma(gg, w23, acc2[k][1]);
        }
    }
    float4 bb = *(const float4*)(b2 + c0);
    float mx0 = -3.4e38f, mx1 = -3.4e38f, mx2 = -3.4e38f, mx3 = -3.4e38f;
#pragma unroll
    for (int k = 0; k < K_; ++k) {
        float h0 = fmaxf(acc2[k][0].x + bb.x, 0.0f);
        float h1 = fmaxf(acc2[k][0].y + bb.y, 0.0f);
        float h2 = fmaxf(acc2[k][1].x + bb.z, 0.0f);
        float h3 = fmaxf(acc2[k][1].y + bb.w, 0.0f);
        mx0 = fmaxf(mx0, h0); mx1 = fmaxf(mx1, h1);
        mx2 = fmaxf(mx2, h2); mx3 = fmaxf(mx3, h3);
    }
    *(float4*)(f2 + q*C2_ + c0) = make_float4(mx0, mx1, mx2, mx3);
}

// ---------------------------------------------------------------- fused adaptive max+avg pool
__global__ __launch_bounds__(256) void pool_kernel(const float* __restrict__ f2,
                                                   float* __restrict__ out) {
    int bo = blockIdx.x;
    int b = bo / OUT_, o = bo % OUT_;
    int c = threadIdx.x;
    float mx = -3.4e38f, sm = 0.0f;
#pragma unroll
    for (int w = 0; w < M_/OUT_; ++w) {
        float v = f2[(b*M_ + o*(M_/OUT_) + w)*C2_ + c];
        mx = fmaxf(mx, v);
        sm += v;
    }
    out[(b*C2_ + c)*OUT_ + o] = mx + sm / (float)(M_/OUT_);
}

// ---------------------------------------------------------------- launch
extern "C" void kernel_launch(void* const* d_in, const int* in_sizes, int n_in,
                              void* d_out, int out_size, void* d_ws, size_t ws_size,
                              hipStream_t stream) {
    const float* x  = (const float*)d_in[0];
    const float* W1 = (const float*)d_in[1];
    const float* b1 = (const float*)d_in[2];
    const float* W2 = (const float*)d_in[3];
    const float* b2 = (const float*)d_in[4];
    float* out = (float*)d_out;

    char* ws = (char*)d_ws;
    size_t off = 0;
    auto alloc = [&](size_t bytes) {
        void* p = ws + off;
        off += (bytes + 255) & ~(size_t)255;
        return p;
    };
    float4* coords4 = (float4*)alloc((size_t)B_*N_*sizeof(float4));     // 2 MB
    float4* sub4    = (float4*)alloc((size_t)B_*SUBP_*sizeof(float4));  // 256 KB
    int*    idx1    = (int*)  alloc((size_t)B_*M_*K_*sizeof(int));      // 2 MB
    int*    idx2    = (int*)  alloc((size_t)B_*M_*K_*sizeof(int));      // 2 MB
    float*  f1      = (float*)alloc((size_t)B_*M_*C1_*sizeof(float));   // 8 MB
    float*  f2      = (float*)alloc((size_t)B_*M_*C2_*sizeof(float));   // 16 MB

    fps_kernel<<<B_, FPS_T, 0, stream>>>(x, coords4, sub4);
    knn_both_kernel<<<2*B_*M_/4, 256, 0, stream>>>(coords4, sub4, idx1, idx2);
    layer1_kernel<<<B_*M_, 128, 0, stream>>>(coords4, sub4, idx1, W1, b1, f1);
    layer2_kernel<<<B_*M_,  64, 0, stream>>>(sub4, f1, idx2, W2, b2, f2);
    pool_kernel<<<B_*OUT_, 256, 0, stream>>>(f2, out);
}

// Round 15
// 1910.878 us; speedup vs baseline: 1.0946x; 1.0326x over previous
//
#include <hip/hip_runtime.h>

#define B_    8
#define N_    8192
#define M_    2000
#define K_    16
#define C1_   128
#define C2_   256
#define OUT_  100
#define SUBP_ 2048   // padded per-batch pitch for subsampled points (KNN2 candidates)

// ---------------------------------------------------------------- FPS v12 (best measured fps 1375-1386us) + fused prep
// fps inner loop is at its structural floor (v13 post-mortem: packing is
// latency-negative; v10: finer splits lose on fixed cost; tail irreducible).
#define FPS_T 512
#define FPS_P 16   // points per thread: 512*16 = 8192

__device__ __forceinline__ unsigned long long umax64(unsigned long long a, unsigned long long b) {
    return a > b ? a : b;
}

// one stage of wave-max on a u64 key via DPP on both halves (identity 0: keys are non-negative)
template<int CTRL>
__device__ __forceinline__ unsigned long long dpp_max_u64(unsigned long long v) {
    int lo = __builtin_amdgcn_update_dpp(0, (int)(unsigned)(v & 0xFFFFFFFFull), CTRL, 0xF, 0xF, true);
    int hi = __builtin_amdgcn_update_dpp(0, (int)(v >> 32),                     CTRL, 0xF, 0xF, true);
    unsigned long long o = ((unsigned long long)(unsigned)hi << 32) | (unsigned)lo;
    return umax64(v, o);
}

// one stage of wave-min on f32 via DPP; identity = self (old=v, bound_ctrl=false)
template<int CTRL>
__device__ __forceinline__ float dpp_min_f32(float v) {
    int o = __builtin_amdgcn_update_dpp(__float_as_int(v), __float_as_int(v), CTRL, 0xF, 0xF, false);
    return fminf(v, __int_as_float(o));
}

__device__ __forceinline__ int spread3(int v) {   // 3 bits -> bits 0,3,6
    return (v & 1) | ((v & 2) << 2) | ((v & 4) << 4);
}

__global__ __launch_bounds__(FPS_T, 1) void fps_kernel(const float* __restrict__ x,
                                                       float4* __restrict__ coords4,
                                                       float4* __restrict__ sub4) {
    int b = blockIdx.x;
    int t = threadIdx.x;
    int w = t >> 6, lane = t & 63;
    const float* X = x + (size_t)b * N_ * 3;
    float4* C4 = coords4 + b * N_;

    __shared__ float4 Clds[N_];                              // 128 KB coords mirror (by ORIGINAL index)
    __shared__ unsigned short sidx[N_];                      // 16 KB sorted->original index map
    __shared__ unsigned int hist[512];                       // counting-sort histogram / cursors
    __shared__ __align__(16) unsigned long long wkey[2][8];  // per-wave max keys, parity double-buffered

    if (t < 512) hist[t] = 0u;
    if (t < SUBP_ - M_)                                      // sentinel pads: never selected by knn2
        sub4[b*SUBP_ + M_ + t] = make_float4(1e15f, 1e15f, 1e15f, 3e30f);
    __syncthreads();

    // ---- phase A (fused prep): read raw x, build float4, mirror to LDS + global, histogram
    int cellv[FPS_P];
#pragma unroll
    for (int j = 0; j < FPS_P; ++j) {
        int i = t + j*FPS_T;
        float xx = X[i*3+0], yy = X[i*3+1], zz = X[i*3+2];
        float ss = fmaf(zz, zz, fmaf(yy, yy, xx*xx));        // ((x^2+y^2)+z^2) — matches old prep
        float4 p = make_float4(xx, yy, zz, ss);
        C4[i] = p;
        Clds[i] = p;
        int cx = (int)(p.x * 8.0f); cx = cx < 0 ? 0 : (cx > 7 ? 7 : cx);
        int cy = (int)(p.y * 8.0f); cy = cy < 0 ? 0 : (cy > 7 ? 7 : cy);
        int cz = (int)(p.z * 8.0f); cz = cz < 0 ? 0 : (cz > 7 ? 7 : cz);
        int cell = (spread3(cx) << 2) | (spread3(cy) << 1) | spread3(cz);   // 9-bit Morton
        cellv[j] = cell;
        atomicAdd(&hist[cell], 1u);
    }
    __syncthreads();

    // ---- phase B: exclusive prefix sum of hist[512] (wave 0)
    if (w == 0) {
        unsigned loc[8], tot = 0u;
#pragma unroll
        for (int c2 = 0; c2 < 8; ++c2) { loc[c2] = hist[lane*8 + c2]; tot += loc[c2]; }
        unsigned pre = tot;
#pragma unroll
        for (int d = 1; d < 64; d <<= 1) {
            unsigned o = __shfl_up(pre, d, 64);
            if (lane >= (unsigned)d) pre += o;
        }
        unsigned run = pre - tot;                            // exclusive base for this lane's 8 cells
#pragma unroll
        for (int c2 = 0; c2 < 8; ++c2) { unsigned v = loc[c2]; hist[lane*8 + c2] = run; run += v; }
    }
    __syncthreads();

    // ---- phase C: scatter original indices into Morton order
#pragma unroll
    for (int j = 0; j < FPS_P; ++j) {
        int i = t + j*FPS_T;
        unsigned pos = atomicAdd(&hist[cellv[j]], 1u);
        sidx[pos] = (unsigned short)i;
    }
    __syncthreads();

    // ---- phase D: wave w owns octant (complement pairing); lane owns 16 sorted points
    int oct = (w < 4) ? w : 11 - w;                          // SIMD pairs {w,w+4} -> opposite corners
    int sbase = oct*1024 + lane*FPS_P;
    float px_[FPS_P], py_[FPS_P], pz_[FPS_P], mind[FPS_P];
    unsigned inv_[FPS_P];
    float wx0 =  1e30f, wy0 =  1e30f, wz0 =  1e30f;
    float wx1 = -1e30f, wy1 = -1e30f, wz1 = -1e30f;
#pragma unroll
    for (int j = 0; j < FPS_P; ++j) {
        int o = (int)sidx[sbase + j];
        float4 p = Clds[o];
        px_[j] = p.x; py_[j] = p.y; pz_[j] = p.z;
        mind[j] = 1e30f;
        inv_[j] = 0xFFFFFFFFu - (unsigned)o;                 // tie -> smaller ORIGINAL index
        wx0 = fminf(wx0, p.x); wx1 = fmaxf(wx1, p.x);
        wy0 = fminf(wy0, p.y); wy1 = fmaxf(wy1, p.y);
        wz0 = fminf(wz0, p.z); wz1 = fmaxf(wz1, p.z);
    }
    // wave bbox: reduce lane bboxes across the wave (one-time)
    for (int s = 1; s < 64; s <<= 1) {
        wx0 = fminf(wx0, __shfl_xor(wx0, s, 64)); wx1 = fmaxf(wx1, __shfl_xor(wx1, s, 64));
        wy0 = fminf(wy0, __shfl_xor(wy0, s, 64)); wy1 = fmaxf(wy1, __shfl_xor(wy1, s, 64));
        wz0 = fminf(wz0, __shfl_xor(wz0, s, 64)); wz1 = fmaxf(wz1, __shfl_xor(wz1, s, 64));
    }

    float4 P0 = Clds[0];                                     // first pick = original index 0
    if (t == 0) sub4[b*SUBP_] = P0;
    float Px = P0.x, Py = P0.y, Pz = P0.z;
    unsigned long long wk = ((unsigned long long)__float_as_uint(1e30f) << 32);  // cached wave key (lane63)
    float wmaxf = 1e30f;                                     // cached wave-max mind (all lanes, via readlane)

    for (int i = 1; i < M_; ++i) {
        // wave-level prune: dmin^2(P, wavebbox) vs cached wave max (skip => bit-exact no-op)
        float qx = fminf(fmaxf(Px, wx0), wx1);
        float qy = fminf(fmaxf(Py, wy0), wy1);
        float qz = fminf(fmaxf(Pz, wz0), wz1);
        float ddx = Px - qx, ddy = Py - qy, ddz = Pz - qz;
        float dmin2 = fmaf(ddz, ddz, fmaf(ddy, ddy, ddx*ddx));
        if (dmin2 * 0.99999f < wmaxf) {                      // ACTIVE: full recompute (all lanes)
            float runmax = -3.4e38f;
            unsigned ib = 0u;
#pragma unroll
            for (int j = 0; j < FPS_P; ++j) {
                float dx = px_[j] - Px, dy = py_[j] - Py, dz = pz_[j] - Pz;
                float d = fmaf(dz, dz, fmaf(dy, dy, dx*dx)); // direct form matches reference FPS
                float m = fminf(mind[j], d);
                mind[j] = m;
                ib = (m > runmax) ? inv_[j] : ib;            // strict >: first max = smallest orig idx
                runmax = fmaxf(runmax, m);
            }
            unsigned long long best = ((unsigned long long)__float_as_uint(runmax) << 32)
                                    | (unsigned long long)ib;
            // wave max into lane 63: row_shr 1/2/4/8 then row_bcast 15/31 (all VALU)
            best = dpp_max_u64<0x111>(best);
            best = dpp_max_u64<0x112>(best);
            best = dpp_max_u64<0x114>(best);
            best = dpp_max_u64<0x118>(best);
            best = dpp_max_u64<0x142>(best);
            best = dpp_max_u64<0x143>(best);
            wk = best;
            wmaxf = __uint_as_float((unsigned)__builtin_amdgcn_readlane((int)(unsigned)(wk >> 32), 63));
        }
        if (lane == 63) wkey[i & 1][w] = wk;
        __syncthreads();
        const ulonglong2* wk2 = (const ulonglong2*)wkey[i & 1];
        ulonglong2 q0 = wk2[0], q1 = wk2[1], q2 = wk2[2], q3 = wk2[3];
        unsigned long long gk = umax64(umax64(umax64(q0.x, q0.y), umax64(q1.x, q1.y)),
                                       umax64(umax64(q2.x, q2.y), umax64(q3.x, q3.y)));
        int last = (int)(0xFFFFFFFFu - (unsigned)(gk & 0xFFFFFFFFull));
        float4 P4 = Clds[last];                              // broadcast LDS read (w = |p|^2 intact)
        Px = P4.x; Py = P4.y; Pz = P4.z;
        if (t == 0) sub4[b*SUBP_ + i] = P4;
    }
}

// ---------------------------------------------------------------- KNN core: 1 wave per query, exact top-16 (set semantics)
// Pass 1: branchless lane-local sorted-16; merge: DPP min chain -> T = exact 16th
// smallest; pass 2: ballot-collect indices (d<T then earliest-index d==T ties —
// matches lax.top_k stability). Collected indices go to a per-wave sink:
// global (knn2 -> idx2 for layer2) or LDS (knn1 -> fused layer1 below).
template<int NCH, int PITCH, bool TO_LDS>
__device__ __forceinline__ void knn_core(const float4* __restrict__ cand,
                                         float4 Q, int b, int base,
                                         int* __restrict__ outIdx, int* __restrict__ ldsIdx) {
    int lane = threadIdx.x & 63;
    const float4* Cb = cand + (size_t)b * PITCH;

    float v[16];
#pragma unroll
    for (int tt = 0; tt < 16; ++tt) v[tt] = 3.4e38f;

#pragma unroll 2
    for (int j = 0; j < NCH; ++j) {
        float4 c = Cb[j*64 + lane];
        float dot = fmaf(c.z, Q.z, fmaf(c.y, Q.y, c.x * Q.x));
        float d = fmaf(-2.0f, dot, Q.w + c.w);   // == (qq+ss) - 2*dot, single rounding
        v[15] = fminf(v[15], d);
#pragma unroll
        for (int tt = 15; tt >= 1; --tt) {       // restore sortedness: bubble toward 0
            float lo = fminf(v[tt-1], v[tt]);
            float hi = fmaxf(v[tt-1], v[tt]);
            v[tt-1] = lo; v[tt] = hi;
        }
    }

    float T = 0.0f;
    for (int r = 0; r < 16; ++r) {               // extract global min 16 times (one entry per round)
        float g = v[0];
        g = dpp_min_f32<0x111>(g);               // row_shr 1/2/4/8 + bcast15/31: lane63 = wave min
        g = dpp_min_f32<0x112>(g);
        g = dpp_min_f32<0x114>(g);
        g = dpp_min_f32<0x118>(g);
        g = dpp_min_f32<0x142>(g);
        g = dpp_min_f32<0x143>(g);
        g = __int_as_float(__builtin_amdgcn_readlane(__float_as_int(g), 63));  // wave-uniform
        unsigned long long mk = __ballot(v[0] == g);
        int fl = __ffsll(mk) - 1;                // exactly one lane consumes (value ties resolved)
        if (lane == fl) {
#pragma unroll
            for (int tt = 0; tt < 15; ++tt) v[tt] = v[tt+1];
            v[15] = 3.4e38f;
        }
        T = g;
    }

    unsigned long long mlt = (1ull << lane) - 1ull;
    int cnt = 0;
    for (int j = 0; j < NCH; ++j) {              // all strictly-closer candidates (<= 15 of them)
        float4 c = Cb[j*64 + lane];
        float dot = fmaf(c.z, Q.z, fmaf(c.y, Q.y, c.x * Q.x));
        float d = fmaf(-2.0f, dot, Q.w + c.w);
        bool lt = d < T;
        unsigned long long m1 = __ballot(lt);
        if (lt) {
            int slot = cnt + __popcll(m1 & mlt);
            if (TO_LDS) ldsIdx[slot] = j*64 + lane; else outIdx[base + slot] = j*64 + lane;
        }
        cnt += __popcll(m1);
    }
    int rem = K_ - cnt;                          // >= 1 (T itself); fill with earliest-index ties
    for (int j = 0; j < NCH && rem > 0; ++j) {
        float4 c = Cb[j*64 + lane];
        float dot = fmaf(c.z, Q.z, fmaf(c.y, Q.y, c.x * Q.x));
        float d = fmaf(-2.0f, dot, Q.w + c.w);
        bool eq = (d == T);
        unsigned long long m2 = __ballot(eq);
        int bef = __popcll(m2 & mlt);
        if (eq && bef < rem) {
            int slot = cnt + bef;
            if (TO_LDS) ldsIdx[slot] = j*64 + lane; else outIdx[base + slot] = j*64 + lane;
        }
        int take = __popcll(m2); if (take > rem) take = rem;
        cnt += take; rem -= take;
    }
}

// R14: knn1 + fused layer1 + knn2 in ONE launch. Blocks [0,4000): knn1 collects
// top-16 into LDS, gathers the 16 neighbor float4s, then the same 64 lanes run
// layer1 (lane owns channels {lane, lane+64}; W1/b1 loads block-invariant ->
// L1-hot). Arithmetic instruction-identical to the old layer1_kernel (same fmaf
// chain/relu; max over k is exact/order-invariant). idx1 never touches global.
// Blocks [4000,8000): knn2 -> idx2 (global) for layer2. Branch is block-uniform;
// knn pass-2 loop exits are wave-uniform (ballot counts) so barriers are safe.
__global__ __launch_bounds__(256) void knn_fused_kernel(const float4* __restrict__ coords4,
                                                        const float4* __restrict__ sub4,
                                                        int* __restrict__ idx2,
                                                        const float* __restrict__ W1,
                                                        const float* __restrict__ b1,
                                                        float* __restrict__ f1) {
    __shared__ int   nbuf[4][K_];                 // per-wave top-16 indices (knn1 branch)
    __shared__ float4 nghl[4][K_];                // per-wave gathered neighbor coords
    int blk = blockIdx.x;
    int wv = threadIdx.x >> 6, lane = threadIdx.x & 63;
    if (blk < B_*M_/4) {
        int q = blk * 4 + wv;
        int b = q / M_, m = q % M_;
        float4 Q = sub4[b * SUBP_ + m];
        knn_core<N_/64, N_, true>(coords4, Q, b, 0, nullptr, nbuf[wv]);
        __syncthreads();                          // nbuf visible block-wide
        if (lane < K_) nghl[wv][lane] = coords4[(size_t)b*N_ + nbuf[wv][lane]];
        __syncthreads();                          // nghl visible
        // ---- layer1: channels c = lane, lane+64
        float w0  = W1[lane],          w1  = W1[C1_ + lane],    w2  = W1[2*C1_ + lane];
        float w3  = W1[3*C1_ + lane],  w4  = W1[4*C1_ + lane],  w5  = W1[5*C1_ + lane];
        float w0b = W1[lane+64],       w1b = W1[C1_ + lane+64], w2b = W1[2*C1_ + lane+64];
        float w3b = W1[3*C1_+lane+64], w4b = W1[4*C1_+lane+64], w5b = W1[5*C1_ + lane+64];
        float bias = b1[lane], biasb = b1[lane+64];
        float mxa = -3.4e38f, mxb = -3.4e38f;
#pragma unroll
        for (int k = 0; k < K_; ++k) {
            float4 n = nghl[wv][k];               // uniform addr -> LDS broadcast
            float rx = n.x - Q.x, ry = n.y - Q.y, rz = n.z - Q.z;
            float s = rx*w0; s = fmaf(ry,w1,s); s = fmaf(rz,w2,s);
            s = fmaf(n.x,w3,s); s = fmaf(n.y,w4,s); s = fmaf(n.z,w5,s);
            s += bias; s = fmaxf(s, 0.0f); mxa = fmaxf(mxa, s);
            float sb = rx*w0b; sb = fmaf(ry,w1b,sb); sb = fmaf(rz,w2b,sb);
            sb = fmaf(n.x,w3b,sb); sb = fmaf(n.y,w4b,sb); sb = fmaf(n.z,w5b,sb);
            sb += biasb; sb = fmaxf(sb, 0.0f); mxb = fmaxf(mxb, sb);
        }
        f1[q*C1_ + lane]      = mxa;
        f1[q*C1_ + lane + 64] = mxb;
    } else {
        int q = (blk - B_*M_/4) * 4 + wv;
        int b = q / M_, m = q % M_;
        float4 Q = sub4[b * SUBP_ + m];
        knn_core<SUBP_/64, SUBP_, false>(sub4, Q, b, q*K_, idx2, nullptr);
    }
}

// ---------------------------------------------------------------- layer 2: feats=[rel(3), fg(128)] x W2[131,256], relu, max over k
// float2 accumulators (__builtin_elementwise_fma) so ISel can emit v_pk_fma_f32.
// Bit-exact: pk halves round identically to scalar fma; accumulation order unchanged.
#define FPAD 20   // row pitch (floats): 16B-aligned rows, odd-ish banking for staging
typedef float v2f __attribute__((ext_vector_type(2)));
__global__ __launch_bounds__(64) void layer2_kernel(const float4* __restrict__ sub4,
        const float* __restrict__ f1, const int* __restrict__ idx2,
        const float* __restrict__ W2, const float* __restrict__ b2,
        float* __restrict__ f2) {
    int q = blockIdx.x;
    int b = q / M_, m = q % M_;
    int t = threadIdx.x;
    __shared__ __align__(16) float feat[(3 + C1_) * FPAD];  // feat[f][k], k=0..15
    __shared__ int nidx[K_];
    float4 Q = sub4[b*SUBP_ + m];
    if (t < K_) {
        int ik = idx2[q*K_ + t];
        nidx[t] = ik;
        float4 n = sub4[b*SUBP_ + ik];
        feat[0*FPAD + t] = n.x - Q.x;
        feat[1*FPAD + t] = n.y - Q.y;
        feat[2*FPAD + t] = n.z - Q.z;
    }
    __syncthreads();
    for (int e = t; e < K_ * C1_; e += 64) {    // stage gathered f1 rows: feat[3+cc][k]
        int k = e >> 7, cc = e & 127;
        feat[(3 + cc)*FPAD + k] = f1[(b*M_ + nidx[k])*C1_ + cc];
    }
    __syncthreads();

    v2f acc2[K_][2];                             // [k][pair]: ch {c0,c0+1}, {c0+2,c0+3}
#pragma unroll
    for (int k = 0; k < K_; ++k) { acc2[k][0] = (v2f){0.f,0.f}; acc2[k][1] = (v2f){0.f,0.f}; }
    int c0 = t * 4;                              // 4 channels per thread, 64 threads = 256 ch
    for (int f = 0; f < 3 + C1_; ++f) {
        float4 wv = *(const float4*)(W2 + f*C2_ + c0);
        v2f w01 = (v2f){wv.x, wv.y}, w23 = (v2f){wv.z, wv.w};
        const float* row = feat + f*FPAD;
        float4 g0 = *(const float4*)(row + 0);
        float4 g1 = *(const float4*)(row + 4);
        float4 g2 = *(const float4*)(row + 8);
        float4 g3 = *(const float4*)(row + 12);
        float gk[16] = {g0.x,g0.y,g0.z,g0.w, g1.x,g1.y,g1.z,g1.w,
                        g2.x,g2.y,g2.z,g2.w, g3.x,g3.y,g3.z,g3.w};
#pragma unroll
        for (int k = 0; k < K_; ++k) {
            v2f gg = (v2f){gk[k], gk[k]};        // splat -> op_sel broadcast in v_pk_fma_f32
            acc2[k][0] = __builtin_elementwise_fma(gg, w01, acc2[k][0]);
            acc2[k][1] = __builtin_elementwise_fma(gg, w23, acc2[k][1]);
        }
    }
    float4 bb = *(const float4*)(b2 + c0);
    float mx0 = -3.4e38f, mx1 = -3.4e38f, mx2 = -3.4e38f, mx3 = -3.4e38f;
#pragma unroll
    for (int k = 0; k < K_; ++k) {
        float h0 = fmaxf(acc2[k][0].x + bb.x, 0.0f);
        float h1 = fmaxf(acc2[k][0].y + bb.y, 0.0f);
        float h2 = fmaxf(acc2[k][1].x + bb.z, 0.0f);
        float h3 = fmaxf(acc2[k][1].y + bb.w, 0.0f);
        mx0 = fmaxf(mx0, h0); mx1 = fmaxf(mx1, h1);
        mx2 = fmaxf(mx2, h2); mx3 = fmaxf(mx3, h3);
    }
    *(float4*)(f2 + q*C2_ + c0) = make_float4(mx0, mx1, mx2, mx3);
}

// ---------------------------------------------------------------- fused adaptive max+avg pool
__global__ __launch_bounds__(256) void pool_kernel(const float* __restrict__ f2,
                                                   float* __restrict__ out) {
    int bo = blockIdx.x;
    int b = bo / OUT_, o = bo % OUT_;
    int c = threadIdx.x;
    float mx = -3.4e38f, sm = 0.0f;
#pragma unroll
    for (int w = 0; w < M_/OUT_; ++w) {
        float v = f2[(b*M_ + o*(M_/OUT_) + w)*C2_ + c];
        mx = fmaxf(mx, v);
        sm += v;
    }
    out[(b*C2_ + c)*OUT_ + o] = mx + sm / (float)(M_/OUT_);
}

// ---------------------------------------------------------------- launch
extern "C" void kernel_launch(void* const* d_in, const int* in_sizes, int n_in,
                              void* d_out, int out_size, void* d_ws, size_t ws_size,
                              hipStream_t stream) {
    const float* x  = (const float*)d_in[0];
    const float* W1 = (const float*)d_in[1];
    const float* b1 = (const float*)d_in[2];
    const float* W2 = (const float*)d_in[3];
    const float* b2 = (const float*)d_in[4];
    float* out = (float*)d_out;

    char* ws = (char*)d_ws;
    size_t off = 0;
    auto alloc = [&](size_t bytes) {
        void* p = ws + off;
        off += (bytes + 255) & ~(size_t)255;
        return p;
    };
    float4* coords4 = (float4*)alloc((size_t)B_*N_*sizeof(float4));     // 2 MB
    float4* sub4    = (float4*)alloc((size_t)B_*SUBP_*sizeof(float4));  // 256 KB
    int*    idx2    = (int*)  alloc((size_t)B_*M_*K_*sizeof(int));      // 2 MB
    float*  f1      = (float*)alloc((size_t)B_*M_*C1_*sizeof(float));   // 8 MB
    float*  f2      = (float*)alloc((size_t)B_*M_*C2_*sizeof(float));   // 16 MB

    fps_kernel<<<B_, FPS_T, 0, stream>>>(x, coords4, sub4);
    knn_fused_kernel<<<2*B_*M_/4, 256, 0, stream>>>(coords4, sub4, idx2, W1, b1, f1);
    layer2_kernel<<<B_*M_, 64, 0, stream>>>(sub4, f1, idx2, W2, b2, f2);
    pool_kernel<<<B_*OUT_, 256, 0, stream>>>(f2, out);
}